// Round 11
// baseline (741.238 us; speedup 1.0000x reference)
//
#include <hip/hip_runtime.h>
#include <math.h>

#define CH 128
#define BSHIFT 9                  // 512 nodes per bucket
#define BNODES (1 << BSHIFT)
#define CHUNKE 2048               // edges per hist/scatter block (parallelism!)

typedef __attribute__((ext_vector_type(8))) short bf16x8;
typedef __attribute__((ext_vector_type(4))) float f32x4;

// ---------------- CSR build: atomic-free counting sort ----------------
__global__ __launch_bounds__(256) void hist_kernel(const int* __restrict__ pe,
                                                   const int* __restrict__ ne,
                                                   int* __restrict__ hb,
                                                   int NBr, int G, int M, int E) {
    const int g = blockIdx.x, s = blockIdx.y, t = threadIdx.x;
    const int* __restrict__ dst = (s ? ne : pe) + E;
    __shared__ int h[512];                      // NBr <= 512
    for (int i = t; i < NBr; i += 256) h[i] = 0;
    __syncthreads();
    const int e0 = g * CHUNKE, e1 = min(e0 + CHUNKE, E);
    for (int e = e0 + t; e < e1; e += 256) atomicAdd(&h[dst[e] >> BSHIFT], 1);
    __syncthreads();
    int* out = hb + (size_t)s * M;
    for (int b = t; b < NBr; b += 256) out[b * G + g] = h[b];
}

__global__ __launch_bounds__(1024) void hscan_kernel(int* __restrict__ hb, int M) {
    const int s = blockIdx.y, t = threadIdx.x;
    int* H = hb + (size_t)s * M;
    const int K = (M + 1023) >> 10;
    const int i0 = t * K, i1 = min(i0 + K, M);
    int sum = 0;
    for (int i = i0; i < i1; ++i) sum += H[i];
    __shared__ int sh[1024];
    sh[t] = sum;
    __syncthreads();
    for (int off = 1; off < 1024; off <<= 1) {
        int v = (t >= off) ? sh[t - off] : 0;
        __syncthreads();
        sh[t] += v;
        __syncthreads();
    }
    int run = sh[t] - sum;
    for (int i = i0; i < i1; ++i) { int v = H[i]; H[i] = run; run += v; }
}

__global__ __launch_bounds__(256) void scatter_kernel(const int* __restrict__ pe,
                                                      const int* __restrict__ ne,
                                                      const int* __restrict__ hb,
                                                      int* __restrict__ tmp,
                                                      int NBr, int G, int M, int E) {
    const int g = blockIdx.x, s = blockIdx.y, t = threadIdx.x;
    const int* __restrict__ ed = s ? ne : pe;
    const int* off = hb + (size_t)s * M;
    __shared__ int cur[512];
    for (int b = t; b < NBr; b += 256) cur[b] = off[b * G + g];
    __syncthreads();
    int* out = tmp + (size_t)s * E;
    const int e0 = g * CHUNKE, e1 = min(e0 + CHUNKE, E);
    for (int e = e0 + t; e < e1; e += 256) {
        const int src = ed[e], d = ed[E + e];
        const int p = atomicAdd(&cur[d >> BSHIFT], 1);   // LDS atomic
        out[p] = (src << BSHIFT) | (d & (BNODES - 1));
    }
}

// 1024 threads: 6 iterations/pass instead of 24 (latency hiding at low grid)
__global__ __launch_bounds__(1024) void bucket_kernel(const int* __restrict__ tmp,
                                                      const int* __restrict__ hb,
                                                      int* __restrict__ row_p,
                                                      int* __restrict__ row_n,
                                                      int* __restrict__ csr_p,
                                                      int* __restrict__ csr_n,
                                                      int NBr, int G, int M, int E, int nN) {
    const int b = blockIdx.x, s = blockIdx.y, t = threadIdx.x;
    const int* off = hb + (size_t)s * M;
    const int lo = off[b * G];
    const int hi = (b + 1 < NBr) ? off[(b + 1) * G] : E;
    const int base = b << BSHIFT;
    const int nloc = min(BNODES, nN - base);
    const int* __restrict__ in = tmp + (size_t)s * E;
    int* __restrict__ row = s ? row_n : row_p;
    int* __restrict__ csr = s ? csr_n : csr_p;
    __shared__ int cnt[BNODES];
    __shared__ int sh[BNODES];
    if (t < BNODES) cnt[t] = 0;
    __syncthreads();
    for (int e = lo + t; e < hi; e += 1024) atomicAdd(&cnt[in[e] & (BNODES - 1)], 1);
    __syncthreads();
    // exclusive scan of cnt[0..512) with 512 active threads (all hit barriers)
    int c = 0;
    if (t < BNODES) { c = cnt[t]; sh[t] = c; }
    __syncthreads();
    for (int o = 1; o < BNODES; o <<= 1) {
        int v = 0;
        if (t < BNODES && t >= o) v = sh[t - o];
        __syncthreads();
        if (t < BNODES) sh[t] += v;
        __syncthreads();
    }
    if (t < BNODES) {
        const int ex = sh[t] - c;
        cnt[t] = lo + ex;                    // becomes write cursor
        if (t < nloc) row[base + t] = lo + ex;
    }
    if (b == NBr - 1 && t == 0) row[nN] = E;
    __syncthreads();
    for (int e = lo + t; e < hi; e += 1024) {
        const int v = in[e];
        const int p = atomicAdd(&cnt[v & (BNODES - 1)], 1);  // LDS atomic
        csr[p] = (v >> BSHIFT) << 8;   // BYTE offset of the 256B bf16 row
    }
}

// ---------------- helpers ----------------
__device__ __forceinline__ float fast_tanh(float x) {
    float e = __expf(2.0f * x);
    return 1.0f - 2.0f * __builtin_amdgcn_rcpf(e + 1.0f);
}

__device__ __forceinline__ unsigned short f2bf(float f) {  // RNE
    unsigned u = __float_as_uint(f);
    u += 0x7fffu + ((u >> 16) & 1u);
    return (unsigned short)(u >> 16);
}

__device__ __forceinline__ float bf_lo(unsigned v) { return __uint_as_float(v << 16); }
__device__ __forceinline__ float bf_hi(unsigned v) { return __uint_as_float(v & 0xffff0000u); }

// ---------------- x -> bf16 convert (once) ----------------
__global__ __launch_bounds__(256) void cvt_kernel(const float* __restrict__ x,
                                                  unsigned short* __restrict__ xb,
                                                  int total8) {
    const int i = blockIdx.x * 256 + threadIdx.x;
    if (i >= total8) return;
    const float4 u0 = ((const float4*)x)[2 * i];
    const float4 u1 = ((const float4*)x)[2 * i + 1];
    union { bf16x8 v; unsigned short u[8]; } o;
    o.u[0] = f2bf(u0.x); o.u[1] = f2bf(u0.y); o.u[2] = f2bf(u0.z); o.u[3] = f2bf(u0.w);
    o.u[4] = f2bf(u1.x); o.u[5] = f2bf(u1.y); o.u[6] = f2bf(u1.z); o.u[7] = f2bf(u1.w);
    ((bf16x8*)xb)[i] = o.v;
}

// ---------------- aggregate ----------------
// One wave per node, both signs. PAIR-LOAD scheme: lanes 0-31 read row i,
// lanes 32-63 read row j (dwordx2 per lane) -> 2 rows per VMEM instruction.
#define P1(csr, e, A0, A1, A2, A3) { \
    const int o0 = csr[e], o1 = csr[e + 1]; \
    const uint2 w = *(const uint2*)(fB + (half ? o1 : o0) + off8); \
    A0 += bf_lo(w.x); A1 += bf_hi(w.x); A2 += bf_lo(w.y); A3 += bf_hi(w.y); }

#define T1(csr, e, A0, A1, A2, A3) { \
    if (half == 0) { \
        const uint2 w = *(const uint2*)(fB + csr[e] + off8); \
        A0 += bf_lo(w.x); A1 += bf_hi(w.x); A2 += bf_lo(w.y); A3 += bf_hi(w.y); } }

__global__ __launch_bounds__(256) void agg_kernel(
    const unsigned short* __restrict__ feat,
    unsigned* __restrict__ aggp, unsigned* __restrict__ aggn,
    const int* __restrict__ row_p, const int* __restrict__ csr_p,
    const int* __restrict__ row_n, const int* __restrict__ csr_n, int nN) {
    const int t = threadIdx.x;
    const int wave = t >> 6;
    const int lane = t & 63;
    const int node = blockIdx.x * 4 + wave;
    if (node >= nN) return;
    const char* __restrict__ fB = (const char*)feat;
    const int half = lane >> 5;
    const int off8 = (lane & 31) * 8;
    // wave-uniform bounds -> SGPR (uniform csr addresses -> s_load)
    int ep = __builtin_amdgcn_readfirstlane(row_p[node]);
    const int e1p = __builtin_amdgcn_readfirstlane(row_p[node + 1]);
    int en = __builtin_amdgcn_readfirstlane(row_n[node]);
    const int e1n = __builtin_amdgcn_readfirstlane(row_n[node + 1]);
    const int degp = e1p - ep;
    const int degn = e1n - en;
    float p0 = 0.f, p1 = 0.f, p2 = 0.f, p3 = 0.f;
    float n0 = 0.f, n1 = 0.f, n2 = 0.f, n3 = 0.f;
    // joint main: 8 pair-loads (16 rows) in flight
    while (ep + 8 <= e1p && en + 8 <= e1n) {
        P1(csr_p, ep,     p0, p1, p2, p3);
        P1(csr_p, ep + 2, p0, p1, p2, p3);
        P1(csr_p, ep + 4, p0, p1, p2, p3);
        P1(csr_p, ep + 6, p0, p1, p2, p3);
        P1(csr_n, en,     n0, n1, n2, n3);
        P1(csr_n, en + 2, n0, n1, n2, n3);
        P1(csr_n, en + 4, n0, n1, n2, n3);
        P1(csr_n, en + 6, n0, n1, n2, n3);
        ep += 8; en += 8;
    }
    // joint mid: 2 pair-loads in flight
    while (ep + 2 <= e1p && en + 2 <= e1n) {
        P1(csr_p, ep, p0, p1, p2, p3);
        P1(csr_n, en, n0, n1, n2, n3);
        ep += 2; en += 2;
    }
    // per-sign pair drains + single tails
    for (; ep + 1 < e1p; ep += 2) P1(csr_p, ep, p0, p1, p2, p3);
    if (ep < e1p) T1(csr_p, ep, p0, p1, p2, p3);
    for (; en + 1 < e1n; en += 2) P1(csr_n, en, n0, n1, n2, n3);
    if (en < e1n) T1(csr_n, en, n0, n1, n2, n3);

    // cross-half reduction: each lane gets the full sum of its 4 channels
    p0 += __shfl_xor(p0, 32); p1 += __shfl_xor(p1, 32);
    p2 += __shfl_xor(p2, 32); p3 += __shfl_xor(p3, 32);
    n0 += __shfl_xor(n0, 32); n1 += __shfl_xor(n1, 32);
    n2 += __shfl_xor(n2, 32); n3 += __shfl_xor(n3, 32);

    const float invp = 1.0f / (float)(degp > 1 ? degp : 1);
    const float invn = 1.0f / (float)(degn > 1 ? degn : 1);
    const int li = lane & 31;
    if (half == 0) {
        uint2 o;
        o.x = (unsigned)f2bf(p0 * invp) | ((unsigned)f2bf(p1 * invp) << 16);
        o.y = (unsigned)f2bf(p2 * invp) | ((unsigned)f2bf(p3 * invp) << 16);
        ((uint2*)(aggp + (size_t)node * 64))[li] = o;
    } else {
        uint2 o;
        o.x = (unsigned)f2bf(n0 * invn) | ((unsigned)f2bf(n1 * invn) << 16);
        o.y = (unsigned)f2bf(n2 * invn) | ((unsigned)f2bf(n3 * invn) << 16);
        ((uint2*)(aggn + (size_t)node * 64))[li] = o;
    }
}

// ---------------- weight packing (+ fused bcat in block 288) ----------------
__global__ __launch_bounds__(64) void wpack_kernel(
    const float* __restrict__ Wp_l, const float* __restrict__ Wp_r,
    const float* __restrict__ Wn_l, const float* __restrict__ Wn_r,
    const float* __restrict__ Wl_pos, const float* __restrict__ Wr_pos,
    const float* __restrict__ Wl_neg, const float* __restrict__ Wr_neg,
    const float* __restrict__ bp, const float* __restrict__ bn,
    const float* __restrict__ b_pos, const float* __restrict__ b_neg,
    unsigned short* __restrict__ Wpk, float* __restrict__ bcat) {
    const int b = blockIdx.x;  // 0..287 = L*96 + ks*8 + nt ; 288 = bcat
    const int lane = threadIdx.x;
    if (b == 288) {
        for (int i = lane; i < 384; i += 64) {
            int L = i >> 7, n = i & 127;
            float v;
            if (L == 0) v = (n < 64) ? bp[n] : bn[n - 64];
            else        v = (n < 64) ? b_pos[(L - 1) * 64 + n] : b_neg[(L - 1) * 64 + (n - 64)];
            bcat[i] = v;
        }
        return;
    }
    const int L = b / 96;
    const int rem = b % 96;
    const int ks = rem / 8, nt = rem % 8;
    const int kb = ks * 32 + (lane >> 4) * 8;
    const int n = nt * 16 + (lane & 15);
    unsigned short v[8];
#pragma unroll
    for (int j = 0; j < 8; ++j) {
        const int k = kb + j;
        float w = 0.f;
        if (L == 0) {
            if (k < 128)      w = (n < 64) ? Wp_l[k * 64 + n] : 0.f;
            else if (k < 256) w = (n < 64) ? 0.f : Wn_l[(k - 128) * 64 + (n - 64)];
            else              w = (n < 64) ? Wp_r[(k - 256) * 64 + n]
                                           : Wn_r[(k - 256) * 64 + (n - 64)];
        } else {
            const float* WLp = Wl_pos + (size_t)(L - 1) * 128 * 64;
            const float* WLn = Wl_neg + (size_t)(L - 1) * 128 * 64;
            const float* WRp = Wr_pos + (size_t)(L - 1) * 64 * 64;
            const float* WRn = Wr_neg + (size_t)(L - 1) * 64 * 64;
            if (k < 64)       w = (n < 64) ? WLp[k * 64 + n] : 0.f;
            else if (k < 128) w = (n < 64) ? 0.f : WLn[(k - 64) * 64 + (n - 64)];
            else if (k < 192) w = (n < 64) ? 0.f : WLn[(64 + k - 128) * 64 + (n - 64)];
            else if (k < 256) w = (n < 64) ? WLp[(64 + k - 192) * 64 + n] : 0.f;
            else if (k < 320) w = (n < 64) ? WRp[(k - 256) * 64 + n] : 0.f;
            else              w = (n < 64) ? 0.f : WRn[(k - 320) * 64 + (n - 64)];
        }
        v[j] = f2bf(w);
    }
    unsigned short* dst = Wpk + (size_t)b * 512 + lane * 8;
#pragma unroll
    for (int j = 0; j < 8; ++j) dst[j] = v[j];
}

// ---------------- MFMA GEMM: z = tanh([aggp|aggn|feat] @ Wcat + bcat) ----------------
// r9 structure (measured best): 64-row blocks, 48KB LDS-staged weights.
// In-place safe: block reads only its own 64 rows before its stores.
template <bool OUTF32>
__global__ __launch_bounds__(256) void gemm_kernel(
    const unsigned short* __restrict__ aggp, const unsigned short* __restrict__ aggn,
    const unsigned short* __restrict__ feat, const unsigned short* __restrict__ Wpk,
    const float* __restrict__ bcat, void* __restrict__ outv, int nN) {
    const int t = threadIdx.x;
    const int wave = __builtin_amdgcn_readfirstlane(t >> 6);
    const int lane = t & 63;
    const int r0 = blockIdx.x * 64 + wave * 16;
    int rowA = r0 + (lane & 15);
    if (rowA >= nN) rowA = nN - 1;  // clamp loads; stores guarded
    const int koff = (lane >> 4) * 8;

    __shared__ unsigned short wlds[48 * 512];   // 48KB: half the layer weights

    f32x4 acc[8];
#pragma unroll
    for (int i = 0; i < 8; ++i) acc[i] = (f32x4){0.f, 0.f, 0.f, 0.f};

    for (int h = 0; h < 2; ++h) {
        // cooperative stage: 48 frags = 3072 bf16x8 vectors, 12 per thread
        {
            const bf16x8* __restrict__ src = (const bf16x8*)(Wpk + (size_t)(h * 48) * 512);
            bf16x8* dst = (bf16x8*)wlds;
#pragma unroll
            for (int j = 0; j < 12; ++j) dst[t + j * 256] = src[t + j * 256];
        }
        __syncthreads();
#pragma unroll
        for (int ksl = 0; ksl < 6; ++ksl) {
            const int ks = h * 6 + ksl;
            const int kcol = (ks & 3) * 32 + koff;
            const unsigned short* ap = (ks < 4) ? aggp : (ks < 8) ? aggn : feat;
            const bf16x8 a = *(const bf16x8*)(ap + (size_t)rowA * CH + kcol);
            const unsigned short* wl = wlds + (size_t)(ksl * 8) * 512 + lane * 8;
#pragma unroll
            for (int nt = 0; nt < 8; ++nt) {
                const bf16x8 bfr = *(const bf16x8*)(wl + nt * 512);
                acc[nt] = __builtin_amdgcn_mfma_f32_16x16x32_bf16(a, bfr, acc[nt], 0, 0, 0);
            }
        }
        __syncthreads();   // protect LDS before next-half staging
    }

    const int col0 = lane & 15;
    const int rq = (lane >> 4) * 4;
#pragma unroll
    for (int nt = 0; nt < 8; ++nt) {
        const int col = nt * 16 + col0;
        const float bias = bcat[col];
#pragma unroll
        for (int r = 0; r < 4; ++r) {
            const int row = r0 + rq + r;
            if (row < nN) {
                const float v = fast_tanh(acc[nt][r] + bias);
                if (OUTF32) ((float*)outv)[(size_t)row * CH + col] = v;
                else ((unsigned short*)outv)[(size_t)row * CH + col] = f2bf(v);
            }
        }
    }
}

// ---------------- launch ----------------
extern "C" void kernel_launch(void* const* d_in, const int* in_sizes, int n_in,
                              void* d_out, int out_size, void* d_ws, size_t ws_size,
                              hipStream_t stream) {
    const float* x      = (const float*)d_in[0];
    const int*   pe     = (const int*)d_in[1];  // [2][E] src,dst
    const int*   ne     = (const int*)d_in[2];
    const float* Wp_l   = (const float*)d_in[3];
    const float* Wp_r   = (const float*)d_in[4];
    const float* bp     = (const float*)d_in[5];
    const float* Wn_l   = (const float*)d_in[6];
    const float* Wn_r   = (const float*)d_in[7];
    const float* bn     = (const float*)d_in[8];
    const float* Wl_pos = (const float*)d_in[9];
    const float* Wr_pos = (const float*)d_in[10];
    const float* b_pos  = (const float*)d_in[11];
    const float* Wl_neg = (const float*)d_in[12];
    const float* Wr_neg = (const float*)d_in[13];
    const float* b_neg  = (const float*)d_in[14];

    const int E = in_sizes[1] / 2;
    const int n = in_sizes[0] / CH;

    const int NBr = (n + BNODES - 1) >> BSHIFT;        // buckets per sign (196)
    const int G   = (E + CHUNKE - 1) / CHUNKE;         // chunks per sign (~586)
    const int M   = NBr * G;                           // hist entries per sign

    // workspace layout
    unsigned short* A    = (unsigned short*)d_ws;   // n*128 bf16
    unsigned short* B    = A + (size_t)n * CH;
    unsigned short* C    = B + (size_t)n * CH;
    unsigned short* Wpk  = C + (size_t)n * CH;      // 3*96*512 = 147456
    float* bcat  = (float*)(Wpk + 147456);          // 384
    int* row_p   = (int*)(bcat + 384);              // n+1
    int* row_n   = row_p + n + 1;                   // n+1
    int* csr_p   = row_n + n + 1;                   // E (byte offsets)
    int* csr_n   = csr_p + E;                       // E (byte offsets)
    int* hb      = csr_n + E;                       // 2*M (~919KB)
    // packed edge temp (2E ints) aliases C during CSR build; afterwards the
    // same region holds xb (bf16 of x) until gemm0 completes; then C becomes
    // the L1 agg output. All transitions stream-ordered -> safe.
    int* tmp     = (int*)C;
    unsigned short* xb = C;

    // CSR build: no global atomics, no memset
    hist_kernel<<<dim3(G, 2), 256, 0, stream>>>(pe, ne, hb, NBr, G, M, E);
    wpack_kernel<<<289, 64, 0, stream>>>(Wp_l, Wp_r, Wn_l, Wn_r,
                                         Wl_pos, Wr_pos, Wl_neg, Wr_neg,
                                         bp, bn, b_pos, b_neg, Wpk, bcat);
    hscan_kernel<<<dim3(1, 2), 1024, 0, stream>>>(hb, M);
    scatter_kernel<<<dim3(G, 2), 256, 0, stream>>>(pe, ne, hb, tmp, NBr, G, M, E);
    bucket_kernel<<<dim3(NBr, 2), 1024, 0, stream>>>(tmp, hb, row_p, row_n,
                                                     csr_p, csr_n, NBr, G, M, E, n);
    // x -> bf16 (after CSR build so xb can overwrite tmp)
    const int total8 = n * CH / 8;
    cvt_kernel<<<(total8 + 255) / 256, 256, 0, stream>>>(x, xb, total8);

    const dim3 agrid((n + 3) / 4), ablock(256);
    const dim3 ggrid((n + 63) / 64), gblock(256);

    // L0: agg(xb) -> A,B ; gemm(A,B,xb) -> z1 in A
    agg_kernel<<<agrid, ablock, 0, stream>>>(
        xb, (unsigned*)A, (unsigned*)B, row_p, csr_p, row_n, csr_n, n);
    gemm_kernel<false><<<ggrid, gblock, 0, stream>>>(
        A, B, xb, Wpk, bcat, A, n);
    // L1: agg(A) -> B,C ; gemm(B,C,A) -> z2 in B
    agg_kernel<<<agrid, ablock, 0, stream>>>(
        A, (unsigned*)B, (unsigned*)C, row_p, csr_p, row_n, csr_n, n);
    gemm_kernel<false><<<ggrid, gblock, 0, stream>>>(
        B, C, A, Wpk + 96 * 512, bcat + 128, B, n);
    // L2: agg(B) -> A,C ; gemm(A,C,B) -> d_out fp32
    agg_kernel<<<agrid, ablock, 0, stream>>>(
        B, (unsigned*)A, (unsigned*)C, row_p, csr_p, row_n, csr_n, n);
    gemm_kernel<true><<<ggrid, gblock, 0, stream>>>(
        A, C, B, Wpk + 2 * 96 * 512, bcat + 256, d_out, n);
}

// Round 12
// 567.727 us; speedup vs baseline: 1.3056x; 1.3056x over previous
//
#include <hip/hip_runtime.h>
#include <math.h>

#define CH 128
#define BSHIFT 9                  // 512 nodes per bucket
#define BNODES (1 << BSHIFT)
#define CHUNKE 2048               // edges per hist/scatter block (parallelism)
#define SEGSZ 4096                // hist entries per scan segment

typedef __attribute__((ext_vector_type(8))) short bf16x8;
typedef __attribute__((ext_vector_type(4))) float f32x4;

// ---------------- CSR build: atomic-free counting sort ----------------
__global__ __launch_bounds__(256) void hist_kernel(const int* __restrict__ pe,
                                                   const int* __restrict__ ne,
                                                   int* __restrict__ hb,
                                                   int NBr, int G, int M, int E) {
    const int g = blockIdx.x, s = blockIdx.y, t = threadIdx.x;
    const int* __restrict__ dst = (s ? ne : pe) + E;
    __shared__ int h[512];                      // NBr <= 512
    for (int i = t; i < NBr; i += 256) h[i] = 0;
    __syncthreads();
    const int e0 = g * CHUNKE, e1 = min(e0 + CHUNKE, E);
    for (int e = e0 + t; e < e1; e += 256) atomicAdd(&h[dst[e] >> BSHIFT], 1);
    __syncthreads();
    int* out = hb + (size_t)s * M;
    for (int b = t; b < NBr; b += 256) out[b * G + g] = h[b];
}

// ---- hierarchical exclusive scan of hb (M entries per sign) ----
__global__ __launch_bounds__(256) void scan_a_kernel(const int* __restrict__ hb,
                                                     int* __restrict__ segsum,
                                                     int M, int NSEG) {
    const int j = blockIdx.x, s = blockIdx.y, t = threadIdx.x;
    const int* H = hb + (size_t)s * M;
    const int base = j * SEGSZ + t * 16;
    int sum = 0;
    if (base + 16 <= M) {
        const int4* p = (const int4*)(H + base);
        const int4 a = p[0], b = p[1], c = p[2], d = p[3];
        sum = (a.x + a.y + a.z + a.w) + (b.x + b.y + b.z + b.w) +
              (c.x + c.y + c.z + c.w) + (d.x + d.y + d.z + d.w);
    } else {
        for (int i = 0; i < 16; ++i)
            if (base + i < M) sum += H[base + i];
    }
    __shared__ int sh[256];
    sh[t] = sum;
    __syncthreads();
    for (int off = 128; off > 0; off >>= 1) {
        if (t < off) sh[t] += sh[t + off];
        __syncthreads();
    }
    if (t == 0) segsum[s * NSEG + j] = sh[0];
}

__global__ __launch_bounds__(1024) void scan_b_kernel(int* __restrict__ segsum, int NSEG) {
    const int s = blockIdx.y, t = threadIdx.x;
    int* S = segsum + (size_t)s * NSEG;
    __shared__ int sh[1024];
    const int v = (t < NSEG) ? S[t] : 0;
    sh[t] = v;
    __syncthreads();
    for (int off = 1; off < 1024; off <<= 1) {
        int u = (t >= off) ? sh[t - off] : 0;
        __syncthreads();
        sh[t] += u;
        __syncthreads();
    }
    if (t < NSEG) S[t] = sh[t] - v;   // exclusive
}

__global__ __launch_bounds__(256) void scan_c_kernel(int* __restrict__ hb,
                                                     const int* __restrict__ segsum,
                                                     int M, int NSEG) {
    const int j = blockIdx.x, s = blockIdx.y, t = threadIdx.x;
    int* H = hb + (size_t)s * M;
    const int base = j * SEGSZ + t * 16;
    int v[16];
    int sum = 0;
    const bool full = (base + 16 <= M);
    if (full) {
        const int4* p = (const int4*)(H + base);
#pragma unroll
        for (int q = 0; q < 4; ++q) {
            const int4 a = p[q];
            v[4 * q] = a.x; v[4 * q + 1] = a.y; v[4 * q + 2] = a.z; v[4 * q + 3] = a.w;
        }
#pragma unroll
        for (int i = 0; i < 16; ++i) sum += v[i];
    } else {
#pragma unroll
        for (int i = 0; i < 16; ++i) {
            v[i] = (base + i < M) ? H[base + i] : 0;
            sum += v[i];
        }
    }
    __shared__ int sh[256];
    sh[t] = sum;
    __syncthreads();
    for (int off = 1; off < 256; off <<= 1) {
        int u = (t >= off) ? sh[t - off] : 0;
        __syncthreads();
        sh[t] += u;
        __syncthreads();
    }
    int run = segsum[s * NSEG + j] + sh[t] - sum;   // global-exclusive at base
    if (full) {
        int out[16];
#pragma unroll
        for (int i = 0; i < 16; ++i) { out[i] = run; run += v[i]; }
        int4* p = (int4*)(H + base);
#pragma unroll
        for (int q = 0; q < 4; ++q)
            p[q] = make_int4(out[4 * q], out[4 * q + 1], out[4 * q + 2], out[4 * q + 3]);
    } else {
#pragma unroll
        for (int i = 0; i < 16; ++i) {
            if (base + i < M) { H[base + i] = run; run += v[i]; }
        }
    }
}

__global__ __launch_bounds__(256) void scatter_kernel(const int* __restrict__ pe,
                                                      const int* __restrict__ ne,
                                                      const int* __restrict__ hb,
                                                      int* __restrict__ tmp,
                                                      int NBr, int G, int M, int E) {
    const int g = blockIdx.x, s = blockIdx.y, t = threadIdx.x;
    const int* __restrict__ ed = s ? ne : pe;
    const int* off = hb + (size_t)s * M;
    __shared__ int cur[512];
    for (int b = t; b < NBr; b += 256) cur[b] = off[b * G + g];
    __syncthreads();
    int* out = tmp + (size_t)s * E;
    const int e0 = g * CHUNKE, e1 = min(e0 + CHUNKE, E);
    for (int e = e0 + t; e < e1; e += 256) {
        const int src = ed[e], d = ed[E + e];
        const int p = atomicAdd(&cur[d >> BSHIFT], 1);   // LDS atomic
        out[p] = (src << BSHIFT) | (d & (BNODES - 1));
    }
}

// 1024 threads: 6 iterations/pass (latency hiding at low grid)
__global__ __launch_bounds__(1024) void bucket_kernel(const int* __restrict__ tmp,
                                                      const int* __restrict__ hb,
                                                      int* __restrict__ row_p,
                                                      int* __restrict__ row_n,
                                                      int* __restrict__ csr_p,
                                                      int* __restrict__ csr_n,
                                                      int NBr, int G, int M, int E, int nN) {
    const int b = blockIdx.x, s = blockIdx.y, t = threadIdx.x;
    const int* off = hb + (size_t)s * M;
    const int lo = off[b * G];
    const int hi = (b + 1 < NBr) ? off[(b + 1) * G] : E;
    const int base = b << BSHIFT;
    const int nloc = min(BNODES, nN - base);
    const int* __restrict__ in = tmp + (size_t)s * E;
    int* __restrict__ row = s ? row_n : row_p;
    int* __restrict__ csr = s ? csr_n : csr_p;
    __shared__ int cnt[BNODES];
    __shared__ int sh[BNODES];
    if (t < BNODES) cnt[t] = 0;
    __syncthreads();
    for (int e = lo + t; e < hi; e += 1024) atomicAdd(&cnt[in[e] & (BNODES - 1)], 1);
    __syncthreads();
    int c = 0;
    if (t < BNODES) { c = cnt[t]; sh[t] = c; }
    __syncthreads();
    for (int o = 1; o < BNODES; o <<= 1) {
        int v = 0;
        if (t < BNODES && t >= o) v = sh[t - o];
        __syncthreads();
        if (t < BNODES) sh[t] += v;
        __syncthreads();
    }
    if (t < BNODES) {
        const int ex = sh[t] - c;
        cnt[t] = lo + ex;                    // becomes write cursor
        if (t < nloc) row[base + t] = lo + ex;
    }
    if (b == NBr - 1 && t == 0) row[nN] = E;
    __syncthreads();
    for (int e = lo + t; e < hi; e += 1024) {
        const int v = in[e];
        const int p = atomicAdd(&cnt[v & (BNODES - 1)], 1);  // LDS atomic
        csr[p] = (v >> BSHIFT) << 8;   // BYTE offset of the 256B bf16 row
    }
}

// ---------------- helpers ----------------
__device__ __forceinline__ float fast_tanh(float x) {
    float e = __expf(2.0f * x);
    return 1.0f - 2.0f * __builtin_amdgcn_rcpf(e + 1.0f);
}

__device__ __forceinline__ unsigned short f2bf(float f) {  // RNE
    unsigned u = __float_as_uint(f);
    u += 0x7fffu + ((u >> 16) & 1u);
    return (unsigned short)(u >> 16);
}

__device__ __forceinline__ float bf_lo(unsigned v) { return __uint_as_float(v << 16); }
__device__ __forceinline__ float bf_hi(unsigned v) { return __uint_as_float(v & 0xffff0000u); }

// ---------------- x -> bf16 convert (once) ----------------
__global__ __launch_bounds__(256) void cvt_kernel(const float* __restrict__ x,
                                                  unsigned short* __restrict__ xb,
                                                  int total8) {
    const int i = blockIdx.x * 256 + threadIdx.x;
    if (i >= total8) return;
    const float4 u0 = ((const float4*)x)[2 * i];
    const float4 u1 = ((const float4*)x)[2 * i + 1];
    union { bf16x8 v; unsigned short u[8]; } o;
    o.u[0] = f2bf(u0.x); o.u[1] = f2bf(u0.y); o.u[2] = f2bf(u0.z); o.u[3] = f2bf(u0.w);
    o.u[4] = f2bf(u1.x); o.u[5] = f2bf(u1.y); o.u[6] = f2bf(u1.z); o.u[7] = f2bf(u1.w);
    ((bf16x8*)xb)[i] = o.v;
}

// ---------------- aggregate ----------------
// One wave per node, both signs. PAIR-LOAD scheme: lanes 0-31 read row i,
// lanes 32-63 read row j (dwordx2 per lane) -> 2 rows per VMEM instruction.
#define P1(csr, e, A0, A1, A2, A3) { \
    const int o0 = csr[e], o1 = csr[e + 1]; \
    const uint2 w = *(const uint2*)(fB + (half ? o1 : o0) + off8); \
    A0 += bf_lo(w.x); A1 += bf_hi(w.x); A2 += bf_lo(w.y); A3 += bf_hi(w.y); }

#define T1(csr, e, A0, A1, A2, A3) { \
    if (half == 0) { \
        const uint2 w = *(const uint2*)(fB + csr[e] + off8); \
        A0 += bf_lo(w.x); A1 += bf_hi(w.x); A2 += bf_lo(w.y); A3 += bf_hi(w.y); } }

__global__ __launch_bounds__(256) void agg_kernel(
    const unsigned short* __restrict__ feat,
    unsigned* __restrict__ aggp, unsigned* __restrict__ aggn,
    const int* __restrict__ row_p, const int* __restrict__ csr_p,
    const int* __restrict__ row_n, const int* __restrict__ csr_n, int nN) {
    const int t = threadIdx.x;
    const int wave = t >> 6;
    const int lane = t & 63;
    const int node = blockIdx.x * 4 + wave;
    if (node >= nN) return;
    const char* __restrict__ fB = (const char*)feat;
    const int half = lane >> 5;
    const int off8 = (lane & 31) * 8;
    // wave-uniform bounds -> SGPR (uniform csr addresses -> s_load)
    int ep = __builtin_amdgcn_readfirstlane(row_p[node]);
    const int e1p = __builtin_amdgcn_readfirstlane(row_p[node + 1]);
    int en = __builtin_amdgcn_readfirstlane(row_n[node]);
    const int e1n = __builtin_amdgcn_readfirstlane(row_n[node + 1]);
    const int degp = e1p - ep;
    const int degn = e1n - en;
    float p0 = 0.f, p1 = 0.f, p2 = 0.f, p3 = 0.f;
    float n0 = 0.f, n1 = 0.f, n2 = 0.f, n3 = 0.f;
    // joint main: 8 pair-loads (16 rows) in flight
    while (ep + 8 <= e1p && en + 8 <= e1n) {
        P1(csr_p, ep,     p0, p1, p2, p3);
        P1(csr_p, ep + 2, p0, p1, p2, p3);
        P1(csr_p, ep + 4, p0, p1, p2, p3);
        P1(csr_p, ep + 6, p0, p1, p2, p3);
        P1(csr_n, en,     n0, n1, n2, n3);
        P1(csr_n, en + 2, n0, n1, n2, n3);
        P1(csr_n, en + 4, n0, n1, n2, n3);
        P1(csr_n, en + 6, n0, n1, n2, n3);
        ep += 8; en += 8;
    }
    // joint mid: 2 pair-loads in flight
    while (ep + 2 <= e1p && en + 2 <= e1n) {
        P1(csr_p, ep, p0, p1, p2, p3);
        P1(csr_n, en, n0, n1, n2, n3);
        ep += 2; en += 2;
    }
    // per-sign pair drains + single tails
    for (; ep + 1 < e1p; ep += 2) P1(csr_p, ep, p0, p1, p2, p3);
    if (ep < e1p) T1(csr_p, ep, p0, p1, p2, p3);
    for (; en + 1 < e1n; en += 2) P1(csr_n, en, n0, n1, n2, n3);
    if (en < e1n) T1(csr_n, en, n0, n1, n2, n3);

    // cross-half reduction: each lane gets the full sum of its 4 channels
    p0 += __shfl_xor(p0, 32); p1 += __shfl_xor(p1, 32);
    p2 += __shfl_xor(p2, 32); p3 += __shfl_xor(p3, 32);
    n0 += __shfl_xor(n0, 32); n1 += __shfl_xor(n1, 32);
    n2 += __shfl_xor(n2, 32); n3 += __shfl_xor(n3, 32);

    const float invp = 1.0f / (float)(degp > 1 ? degp : 1);
    const float invn = 1.0f / (float)(degn > 1 ? degn : 1);
    const int li = lane & 31;
    if (half == 0) {
        uint2 o;
        o.x = (unsigned)f2bf(p0 * invp) | ((unsigned)f2bf(p1 * invp) << 16);
        o.y = (unsigned)f2bf(p2 * invp) | ((unsigned)f2bf(p3 * invp) << 16);
        ((uint2*)(aggp + (size_t)node * 64))[li] = o;
    } else {
        uint2 o;
        o.x = (unsigned)f2bf(n0 * invn) | ((unsigned)f2bf(n1 * invn) << 16);
        o.y = (unsigned)f2bf(n2 * invn) | ((unsigned)f2bf(n3 * invn) << 16);
        ((uint2*)(aggn + (size_t)node * 64))[li] = o;
    }
}

// ---------------- weight packing (+ fused bcat in block 288) ----------------
__global__ __launch_bounds__(64) void wpack_kernel(
    const float* __restrict__ Wp_l, const float* __restrict__ Wp_r,
    const float* __restrict__ Wn_l, const float* __restrict__ Wn_r,
    const float* __restrict__ Wl_pos, const float* __restrict__ Wr_pos,
    const float* __restrict__ Wl_neg, const float* __restrict__ Wr_neg,
    const float* __restrict__ bp, const float* __restrict__ bn,
    const float* __restrict__ b_pos, const float* __restrict__ b_neg,
    unsigned short* __restrict__ Wpk, float* __restrict__ bcat) {
    const int b = blockIdx.x;  // 0..287 = L*96 + ks*8 + nt ; 288 = bcat
    const int lane = threadIdx.x;
    if (b == 288) {
        for (int i = lane; i < 384; i += 64) {
            int L = i >> 7, n = i & 127;
            float v;
            if (L == 0) v = (n < 64) ? bp[n] : bn[n - 64];
            else        v = (n < 64) ? b_pos[(L - 1) * 64 + n] : b_neg[(L - 1) * 64 + (n - 64)];
            bcat[i] = v;
        }
        return;
    }
    const int L = b / 96;
    const int rem = b % 96;
    const int ks = rem / 8, nt = rem % 8;
    const int kb = ks * 32 + (lane >> 4) * 8;
    const int n = nt * 16 + (lane & 15);
    unsigned short v[8];
#pragma unroll
    for (int j = 0; j < 8; ++j) {
        const int k = kb + j;
        float w = 0.f;
        if (L == 0) {
            if (k < 128)      w = (n < 64) ? Wp_l[k * 64 + n] : 0.f;
            else if (k < 256) w = (n < 64) ? 0.f : Wn_l[(k - 128) * 64 + (n - 64)];
            else              w = (n < 64) ? Wp_r[(k - 256) * 64 + n]
                                           : Wn_r[(k - 256) * 64 + (n - 64)];
        } else {
            const float* WLp = Wl_pos + (size_t)(L - 1) * 128 * 64;
            const float* WLn = Wl_neg + (size_t)(L - 1) * 128 * 64;
            const float* WRp = Wr_pos + (size_t)(L - 1) * 64 * 64;
            const float* WRn = Wr_neg + (size_t)(L - 1) * 64 * 64;
            if (k < 64)       w = (n < 64) ? WLp[k * 64 + n] : 0.f;
            else if (k < 128) w = (n < 64) ? 0.f : WLn[(k - 64) * 64 + (n - 64)];
            else if (k < 192) w = (n < 64) ? 0.f : WLn[(64 + k - 128) * 64 + (n - 64)];
            else if (k < 256) w = (n < 64) ? WLp[(64 + k - 192) * 64 + n] : 0.f;
            else if (k < 320) w = (n < 64) ? WRp[(k - 256) * 64 + n] : 0.f;
            else              w = (n < 64) ? 0.f : WRn[(k - 320) * 64 + (n - 64)];
        }
        v[j] = f2bf(w);
    }
    unsigned short* dst = Wpk + (size_t)b * 512 + lane * 8;
#pragma unroll
    for (int j = 0; j < 8; ++j) dst[j] = v[j];
}

// ---------------- MFMA GEMM: z = tanh([aggp|aggn|feat] @ Wcat + bcat) ----------------
// r9 structure (measured best): 64-row blocks, 48KB LDS-staged weights.
// In-place safe: block reads only its own 64 rows before its stores.
template <bool OUTF32>
__global__ __launch_bounds__(256) void gemm_kernel(
    const unsigned short* __restrict__ aggp, const unsigned short* __restrict__ aggn,
    const unsigned short* __restrict__ feat, const unsigned short* __restrict__ Wpk,
    const float* __restrict__ bcat, void* __restrict__ outv, int nN) {
    const int t = threadIdx.x;
    const int wave = __builtin_amdgcn_readfirstlane(t >> 6);
    const int lane = t & 63;
    const int r0 = blockIdx.x * 64 + wave * 16;
    int rowA = r0 + (lane & 15);
    if (rowA >= nN) rowA = nN - 1;  // clamp loads; stores guarded
    const int koff = (lane >> 4) * 8;

    __shared__ unsigned short wlds[48 * 512];   // 48KB: half the layer weights

    f32x4 acc[8];
#pragma unroll
    for (int i = 0; i < 8; ++i) acc[i] = (f32x4){0.f, 0.f, 0.f, 0.f};

    for (int h = 0; h < 2; ++h) {
        // cooperative stage: 48 frags = 3072 bf16x8 vectors, 12 per thread
        {
            const bf16x8* __restrict__ src = (const bf16x8*)(Wpk + (size_t)(h * 48) * 512);
            bf16x8* dst = (bf16x8*)wlds;
#pragma unroll
            for (int j = 0; j < 12; ++j) dst[t + j * 256] = src[t + j * 256];
        }
        __syncthreads();
#pragma unroll
        for (int ksl = 0; ksl < 6; ++ksl) {
            const int ks = h * 6 + ksl;
            const int kcol = (ks & 3) * 32 + koff;
            const unsigned short* ap = (ks < 4) ? aggp : (ks < 8) ? aggn : feat;
            const bf16x8 a = *(const bf16x8*)(ap + (size_t)rowA * CH + kcol);
            const unsigned short* wl = wlds + (size_t)(ksl * 8) * 512 + lane * 8;
#pragma unroll
            for (int nt = 0; nt < 8; ++nt) {
                const bf16x8 bfr = *(const bf16x8*)(wl + nt * 512);
                acc[nt] = __builtin_amdgcn_mfma_f32_16x16x32_bf16(a, bfr, acc[nt], 0, 0, 0);
            }
        }
        __syncthreads();   // protect LDS before next-half staging
    }

    const int col0 = lane & 15;
    const int rq = (lane >> 4) * 4;
#pragma unroll
    for (int nt = 0; nt < 8; ++nt) {
        const int col = nt * 16 + col0;
        const float bias = bcat[col];
#pragma unroll
        for (int r = 0; r < 4; ++r) {
            const int row = r0 + rq + r;
            if (row < nN) {
                const float v = fast_tanh(acc[nt][r] + bias);
                if (OUTF32) ((float*)outv)[(size_t)row * CH + col] = v;
                else ((unsigned short*)outv)[(size_t)row * CH + col] = f2bf(v);
            }
        }
    }
}

// ---------------- launch ----------------
extern "C" void kernel_launch(void* const* d_in, const int* in_sizes, int n_in,
                              void* d_out, int out_size, void* d_ws, size_t ws_size,
                              hipStream_t stream) {
    const float* x      = (const float*)d_in[0];
    const int*   pe     = (const int*)d_in[1];  // [2][E] src,dst
    const int*   ne     = (const int*)d_in[2];
    const float* Wp_l   = (const float*)d_in[3];
    const float* Wp_r   = (const float*)d_in[4];
    const float* bp     = (const float*)d_in[5];
    const float* Wn_l   = (const float*)d_in[6];
    const float* Wn_r   = (const float*)d_in[7];
    const float* bn     = (const float*)d_in[8];
    const float* Wl_pos = (const float*)d_in[9];
    const float* Wr_pos = (const float*)d_in[10];
    const float* b_pos  = (const float*)d_in[11];
    const float* Wl_neg = (const float*)d_in[12];
    const float* Wr_neg = (const float*)d_in[13];
    const float* b_neg  = (const float*)d_in[14];

    const int E = in_sizes[1] / 2;
    const int n = in_sizes[0] / CH;

    const int NBr  = (n + BNODES - 1) >> BSHIFT;       // buckets per sign (196)
    const int G    = (E + CHUNKE - 1) / CHUNKE;        // chunks per sign (~586)
    const int M    = NBr * G;                          // hist entries per sign
    const int NSEG = (M + SEGSZ - 1) / SEGSZ;          // scan segments (~29)

    // workspace layout
    unsigned short* A    = (unsigned short*)d_ws;   // n*128 bf16
    unsigned short* B    = A + (size_t)n * CH;
    unsigned short* C    = B + (size_t)n * CH;
    unsigned short* Wpk  = C + (size_t)n * CH;      // 3*96*512 = 147456
    float* bcat  = (float*)(Wpk + 147456);          // 384
    int* row_p   = (int*)(bcat + 384);              // n+1
    int* row_n   = row_p + n + 1;                   // n+1
    int* csr_p   = row_n + n + 1;                   // E (byte offsets)
    int* csr_n   = csr_p + E;                       // E (byte offsets)
    int* hb      = csr_n + E;                       // 2*M (~919KB)
    int* segsum  = hb + (size_t)2 * M;              // 2*NSEG
    // packed edge temp (2E ints) aliases C during CSR build; afterwards the
    // same region holds xb (bf16 of x) until gemm0 completes; then C becomes
    // the L1 agg output. All transitions stream-ordered -> safe.
    int* tmp     = (int*)C;
    unsigned short* xb = C;

    // CSR build: no global atomics, no memset
    hist_kernel<<<dim3(G, 2), 256, 0, stream>>>(pe, ne, hb, NBr, G, M, E);
    wpack_kernel<<<289, 64, 0, stream>>>(Wp_l, Wp_r, Wn_l, Wn_r,
                                         Wl_pos, Wr_pos, Wl_neg, Wr_neg,
                                         bp, bn, b_pos, b_neg, Wpk, bcat);
    scan_a_kernel<<<dim3(NSEG, 2), 256, 0, stream>>>(hb, segsum, M, NSEG);
    scan_b_kernel<<<dim3(1, 2), 1024, 0, stream>>>(segsum, NSEG);
    scan_c_kernel<<<dim3(NSEG, 2), 256, 0, stream>>>(hb, segsum, M, NSEG);
    scatter_kernel<<<dim3(G, 2), 256, 0, stream>>>(pe, ne, hb, tmp, NBr, G, M, E);
    bucket_kernel<<<dim3(NBr, 2), 1024, 0, stream>>>(tmp, hb, row_p, row_n,
                                                     csr_p, csr_n, NBr, G, M, E, n);
    // x -> bf16 (after CSR build so xb can overwrite tmp)
    const int total8 = n * CH / 8;
    cvt_kernel<<<(total8 + 255) / 256, 256, 0, stream>>>(x, xb, total8);

    const dim3 agrid((n + 3) / 4), ablock(256);
    const dim3 ggrid((n + 63) / 64), gblock(256);

    // L0: agg(xb) -> A,B ; gemm(A,B,xb) -> z1 in A
    agg_kernel<<<agrid, ablock, 0, stream>>>(
        xb, (unsigned*)A, (unsigned*)B, row_p, csr_p, row_n, csr_n, n);
    gemm_kernel<false><<<ggrid, gblock, 0, stream>>>(
        A, B, xb, Wpk, bcat, A, n);
    // L1: agg(A) -> B,C ; gemm(B,C,A) -> z2 in B
    agg_kernel<<<agrid, ablock, 0, stream>>>(
        A, (unsigned*)B, (unsigned*)C, row_p, csr_p, row_n, csr_n, n);
    gemm_kernel<false><<<ggrid, gblock, 0, stream>>>(
        B, C, A, Wpk + 96 * 512, bcat + 128, B, n);
    // L2: agg(B) -> A,C ; gemm(A,C,B) -> d_out fp32
    agg_kernel<<<agrid, ablock, 0, stream>>>(
        B, (unsigned*)A, (unsigned*)C, row_p, csr_p, row_n, csr_n, n);
    gemm_kernel<true><<<ggrid, gblock, 0, stream>>>(
        A, C, B, Wpk + 2 * 96 * 512, bcat + 256, d_out, n);
}